// Round 9
// baseline (305.891 us; speedup 1.0000x reference)
//
#include <hip/hip_runtime.h>
#include <math.h>

#define BB 8
#define NCC 1024
#define NTT 1024
#define HH 128
#define DYY 32
#define NTB 16                   // 512 blocks x 512 threads
#define LOG2E 1.44269504088896340736f

// r8: R4's exact compute structure (best measured: 41.7us, lowest VALU work)
// with LDS arenas TIME-ALIASED 55.2KB -> 28.9KB so 2 blocks/CU co-reside.
// Occupancy ladder evidence: 34.8KB -> occ 31% (R1, 2 blk/CU); 55.3/74.2KB ->
// occ 18-21% (R4/R6, 1 blk/CU). R4 at 2 waves/SIMD cannot hide ds_read
// (~120cy) / L2 (~200cy) latency -> VALUBusy pinned ~33%.
// (r8 attempt hit an infra failure -- container died twice, no counters --
// source re-audited for bounds/races/aliasing and resubmitted unchanged.)
//   phase 1:  HB[0,2112) RED[2112,2496) WCH[2496,6592)   (dead after sigl bar)
//   phase 2:  YCB[0,4096) XCB[4096,7168)                 (aliases phase 1)
//   epilogue: CMB[0,4224) SL[4224,4352)                  (barrier before dump)
//   SIGL[7168,7216) disjoint from all.
#define HB 0
#define RED 2112
#define WCH 2496
#define YCB 0
#define XCB 4096
#define SIGL 7168
#define SMEM_SZ 7216             // 28.9 KB
#define CMB 0
#define SL 4224
#define HSTRIDE 132              // mult of 4 (aligned b128); p vs p+8 = 2-way = free

// Wave-autonomous staging (r4-proven): W cols [16w,16w+16) and yc rows
// [128w,128w+128) are read ONLY by wave w -> wave-private LDS double-buffer,
// compiler-managed vmcnt/lgkmcnt, no barriers inside either pipeline.
// XCD swizzle (r6/r7-proven: FETCH 5.2->1.2MB): batch b pinned to XCD b.
// Phase 2 e-dedup 1x: 2 exp/lane/tile, partner via shfl_xor(16).
// P<=0 (sig>0) => exp(P)<=1: no max subtraction.

#define ACC16(E, PTR)                                                          \
    do {                                                                       \
        const float4* yv_ = (const float4*)(PTR);                              \
        const float4 q0_ = yv_[0], q1_ = yv_[1], q2_ = yv_[2], q3_ = yv_[3];   \
        acc[0] = fmaf(E, q0_.x, acc[0]);                                       \
        acc[1] = fmaf(E, q0_.y, acc[1]);                                       \
        acc[2] = fmaf(E, q0_.z, acc[2]);                                       \
        acc[3] = fmaf(E, q0_.w, acc[3]);                                       \
        acc[4] = fmaf(E, q1_.x, acc[4]);                                       \
        acc[5] = fmaf(E, q1_.y, acc[5]);                                       \
        acc[6] = fmaf(E, q1_.z, acc[6]);                                       \
        acc[7] = fmaf(E, q1_.w, acc[7]);                                       \
        acc[8] = fmaf(E, q2_.x, acc[8]);                                       \
        acc[9] = fmaf(E, q2_.y, acc[9]);                                       \
        acc[10] = fmaf(E, q2_.z, acc[10]);                                     \
        acc[11] = fmaf(E, q2_.w, acc[11]);                                     \
        acc[12] = fmaf(E, q3_.x, acc[12]);                                     \
        acc[13] = fmaf(E, q3_.y, acc[13]);                                     \
        acc[14] = fmaf(E, q3_.z, acc[14]);                                     \
        acc[15] = fmaf(E, q3_.w, acc[15]);                                     \
    } while (0)

__global__ __launch_bounds__(512, 2) void k_fused(const float* __restrict__ xc,
                                                  const float* __restrict__ yc,
                                                  const float* __restrict__ xt,
                                                  const float* __restrict__ W0,
                                                  const float* __restrict__ b0,
                                                  const float* __restrict__ W1,
                                                  const float* __restrict__ b1,
                                                  const float* __restrict__ W2,
                                                  const float* __restrict__ b2,
                                                  const float* __restrict__ W3,
                                                  const float* __restrict__ b3,
                                                  float* __restrict__ out) {
    const int tid = threadIdx.x;
    const int phys = blockIdx.x;
    const int bid = (phys & 7) * 64 + (phys >> 3);   // XCD swizzle: batch<->XCD
    const int t0 = bid * NTB;
    const int b = bid >> 6;              // 64 blocks per batch
    const int wv = tid >> 6;             // wave 0..7
    const int lane = tid & 63;

    __shared__ float smem[SMEM_SZ];

    const float4* __restrict__ ycG4 = (const float4*)(yc + (size_t)b * NCC * DYY);
    const float4* __restrict__ xcG4 = (const float4*)(xc + (size_t)b * NCC * 3);

    float* ycw = smem + YCB + wv * 512;  // wave-private: 2 bufs x 256 floats
    float* xcw = smem + XCB + wv * 384;  // wave-private: 128 rows x 3
    const int ybase = wv * 1024;         // f4 index of wave's first yc row

    // ================= phase 1: MLP (r4 structure, proven) =================
    const int jg = tid >> 4;             // 0..31 col-group (4 cols)
    const int p = tid & 15;              // 0..15 point
    const int j0 = jg * 4;
    const int jl4 = (jg & 3) * 4;        // col offset within the wave's W slice
    float* hrow = smem + HB + p * HSTRIDE;

    {
        const float* xr = xt + (size_t)(t0 + p) * 3;
        const float x0 = xr[0], x1 = xr[1], x2 = xr[2];
        const float4* W0v = (const float4*)W0;
        const float4 w0a = W0v[jg], w0b = W0v[32 + jg], w0c = W0v[64 + jg];
        const float4 bb0 = ((const float4*)b0)[jg];
        float4 h0;
        h0.x = fmaxf(fmaf(x0, w0a.x, fmaf(x1, w0b.x, fmaf(x2, w0c.x, bb0.x))), 0.f);
        h0.y = fmaxf(fmaf(x0, w0a.y, fmaf(x1, w0b.y, fmaf(x2, w0c.y, bb0.y))), 0.f);
        h0.z = fmaxf(fmaf(x0, w0a.z, fmaf(x1, w0b.z, fmaf(x2, w0c.z, bb0.z))), 0.f);
        h0.w = fmaxf(fmaf(x0, w0a.w, fmaf(x1, w0b.w, fmaf(x2, w0c.w, bb0.w))), 0.f);
        *(float4*)(hrow + j0) = h0;
    }

    const int gWb = (lane >> 2) * 32 + wv * 4 + (lane & 3);
    float* wwb = smem + WCH + wv * 512;
    const float4* __restrict__ W1v = (const float4*)W1;
    const float4* __restrict__ W2v = (const float4*)W2;

    float4 wA0 = W1v[gWb], wA1 = W1v[gWb + 512];
    __syncthreads();                     // h(L0) visible

    auto run_layer = [&](const float4* __restrict__ Wv, const float4 bi,
                         float4 r0, float4 r1) -> float4 {
        float a0 = bi.x, a1 = bi.y, a2 = bi.z, a3 = bi.w;
        ((float4*)wwb)[lane] = r0;
        float4 wcur = r1;
#pragma unroll
        for (int c = 0; c < 8; ++c) {
            float4 wnext;
            if (c < 6) wnext = Wv[gWb + (c + 2) * 512];
            if (c < 7) ((float4*)(wwb + ((c + 1) & 1) * 256))[lane] = wcur;
            const float* wbc = wwb + (c & 1) * 256;
#pragma unroll
            for (int q = 0; q < 4; ++q) {
                const float4 ch = *(const float4*)(hrow + c * 16 + q * 4);
                const float4 k0 = *(const float4*)(wbc + (q * 4 + 0) * 16 + jl4);
                const float4 k1 = *(const float4*)(wbc + (q * 4 + 1) * 16 + jl4);
                const float4 k2 = *(const float4*)(wbc + (q * 4 + 2) * 16 + jl4);
                const float4 k3 = *(const float4*)(wbc + (q * 4 + 3) * 16 + jl4);
                a0 = fmaf(ch.x, k0.x, a0);
                a1 = fmaf(ch.x, k0.y, a1);
                a2 = fmaf(ch.x, k0.z, a2);
                a3 = fmaf(ch.x, k0.w, a3);
                a0 = fmaf(ch.y, k1.x, a0);
                a1 = fmaf(ch.y, k1.y, a1);
                a2 = fmaf(ch.y, k1.z, a2);
                a3 = fmaf(ch.y, k1.w, a3);
                a0 = fmaf(ch.z, k2.x, a0);
                a1 = fmaf(ch.z, k2.y, a1);
                a2 = fmaf(ch.z, k2.z, a2);
                a3 = fmaf(ch.z, k2.w, a3);
                a0 = fmaf(ch.w, k3.x, a0);
                a1 = fmaf(ch.w, k3.y, a1);
                a2 = fmaf(ch.w, k3.z, a2);
                a3 = fmaf(ch.w, k3.w, a3);
            }
            wcur = wnext;
        }
        float4 r;
        r.x = fmaxf(a0, 0.f);
        r.y = fmaxf(a1, 0.f);
        r.z = fmaxf(a2, 0.f);
        r.w = fmaxf(a3, 0.f);
        return r;
    };

    float4 oL1 = run_layer(W1v, ((const float4*)b1)[jg], wA0, wA1);
    float4 wB0 = W2v[gWb], wB1 = W2v[gWb + 512];
    __syncthreads();                     // h(L0) reads done
    *(float4*)(hrow + j0) = oL1;
    __syncthreads();                     // h(L1) visible
    float4 oL2 = run_layer(W2v, ((const float4*)b2)[jg], wB0, wB1);

    // ---- issue phase-2 staging loads NOW: latency hides under L3+sigl ----
    float4 ty0 = ycG4[ybase + lane];            // yc tiles 0,1
    float4 ty1 = ycG4[ybase + 64 + lane];
    float4 tx0, tx1;
    if (lane < 48) {                            // full xc slice (128 rows)
        tx0 = xcG4[wv * 96 + lane];
        tx1 = xcG4[wv * 96 + 48 + lane];
    }

    {
        const float4* W3v = (const float4*)W3;
        const float4 wr0 = W3v[jg * 3 + 0];
        const float4 wr1 = W3v[jg * 3 + 1];
        const float4 wr2 = W3v[jg * 3 + 2];
        float p0 = oL2.x * wr0.x + oL2.y * wr0.w + oL2.z * wr1.z + oL2.w * wr2.y;
        float p1 = oL2.x * wr0.y + oL2.y * wr1.x + oL2.z * wr1.w + oL2.w * wr2.z;
        float p2 = oL2.x * wr0.z + oL2.y * wr1.y + oL2.z * wr2.x + oL2.w * wr2.w;
        p0 += __shfl_xor(p0, 16, 64);    // lane bits 4,5 = jg&3: reduce 4 jg
        p0 += __shfl_xor(p0, 32, 64);
        p1 += __shfl_xor(p1, 16, 64);
        p1 += __shfl_xor(p1, 32, 64);
        p2 += __shfl_xor(p2, 16, 64);
        p2 += __shfl_xor(p2, 32, 64);
        if (lane < 16) {                 // lane = p here
            smem[RED + wv * 48 + lane * 3 + 0] = p0;
            smem[RED + wv * 48 + lane * 3 + 1] = p1;
            smem[RED + wv * 48 + lane * 3 + 2] = p2;
        }
    }
    __syncthreads();
    if (tid < 48) {
        const int r = tid / 3, cix = tid - r * 3;
        float v = b3[cix];
#pragma unroll
        for (int g = 0; g < 8; ++g) v += smem[RED + g * 48 + r * 3 + cix];
        smem[SIGL + r * 3 + cix] = __expf(v) * LOG2E;
    }
    __syncthreads();                     // sigl ready; phase-1 arenas DEAD

    // ---- park staged data into the (re-used) phase-2 arenas ----
    ((float4*)ycw)[lane] = ty0;
    ((float4*)(ycw + 256))[lane] = ty1;
    if (lane < 48) {
        ((float4*)xcw)[lane] = tx0;
        ((float4*)xcw)[lane + 48] = tx1;
    }

    // ========== phase 2: attention, wave-autonomous, barrier-free ==========
    const int tl = lane & 15;            // target within block
    const int dg = (lane >> 4) & 1;      // d-half
    const int ns = lane >> 5;            // n-half within the wave's 8-row tile
    const int dg16 = dg * 16;
    const int rown = ns * 4 + dg * 2;        // own e rows
    const int rowo = ns * 4 + 2 - dg * 2;    // partner e rows (via shfl)

    const float s0 = smem[SIGL + tl * 3 + 0];
    const float s1 = smem[SIGL + tl * 3 + 1];
    const float s2 = smem[SIGL + tl * 3 + 2];
    const float* ar = xt + (size_t)(t0 + tl) * 3;
    const float a0 = ar[0], a1 = ar[1], a2 = ar[2];

    float acc[16];
#pragma unroll
    for (int i = 0; i < 16; ++i) acc[i] = 0.f;
    float l = 0.f;

#pragma unroll 2
    for (int t = 0; t < 16; ++t) {
        float4 ynext;
        if (t < 14) ynext = ycG4[ybase + (t + 2) * 64 + lane];   // issue early
        const float* yb = ycw + (t & 1) * 256;
        const float* xb = xcw + t * 24;

        float d0 = xb[rown * 3 + 0] - a0;
        float d1 = xb[rown * 3 + 1] - a1;
        float d2 = xb[rown * 3 + 2] - a2;
        float pp = fmaf(s0, d0 * d0, fmaf(s1, d1 * d1, s2 * (d2 * d2)));
        const float eo0 = exp2f(-pp);
        d0 = xb[rown * 3 + 3] - a0;
        d1 = xb[rown * 3 + 4] - a1;
        d2 = xb[rown * 3 + 5] - a2;
        pp = fmaf(s0, d0 * d0, fmaf(s1, d1 * d1, s2 * (d2 * d2)));
        const float eo1 = exp2f(-pp);
        l += eo0 + eo1;
        const float ex0 = __shfl_xor(eo0, 16, 64);   // partner's rows
        const float ex1 = __shfl_xor(eo1, 16, 64);

        ACC16(eo0, yb + rown * 32 + dg16);
        ACC16(eo1, yb + (rown + 1) * 32 + dg16);
        ACC16(ex0, yb + rowo * 32 + dg16);
        ACC16(ex1, yb + (rowo + 1) * 32 + dg16);

        if (t < 14)                      // buf just freed; same-wave DS order
            ((float4*)(ycw + (t & 1) * 256))[lane] = ynext;
    }

    // ---- merge dg-pair l, merge ns pairs ----
    l += __shfl_xor(l, 16, 64);          // l was dg-split by the e-dedup
#pragma unroll
    for (int i = 0; i < 16; ++i) acc[i] += __shfl_xor(acc[i], 32, 64);
    l += __shfl_xor(l, 32, 64);

    __syncthreads();                     // all phase-2 LDS reads done: CMB may
                                         // now overwrite YCB/XCB
    if (ns == 0) {
#pragma unroll
        for (int i = 0; i < 16; ++i)
            smem[CMB + (wv * 16 + tl) * 33 + dg16 + i] = acc[i];
        if (dg == 0) smem[SL + wv * 16 + tl] = l;
    }
    __syncthreads();
    {
        const int rtl = tid >> 5, d = tid & 31;   // each thread owns one output
        float ssum = 0.f, lsum = 0.f;
#pragma unroll
        for (int ww = 0; ww < 8; ++ww) {
            ssum += smem[CMB + (ww * 16 + rtl) * 33 + d];
            lsum += smem[SL + ww * 16 + rtl];
        }
        out[(size_t)(t0 + rtl) * DYY + d] = ssum / lsum;
    }
}

extern "C" void kernel_launch(void* const* d_in, const int* in_sizes, int n_in,
                              void* d_out, int out_size, void* d_ws, size_t ws_size,
                              hipStream_t stream) {
    const float* xc = (const float*)d_in[0];
    const float* yc = (const float*)d_in[1];
    const float* xt = (const float*)d_in[2];
    const float* W0 = (const float*)d_in[3];
    const float* b0 = (const float*)d_in[4];
    const float* W1 = (const float*)d_in[5];
    const float* b1 = (const float*)d_in[6];
    const float* W2 = (const float*)d_in[7];
    const float* b2 = (const float*)d_in[8];
    const float* W3 = (const float*)d_in[9];
    const float* b3 = (const float*)d_in[10];
    float* out = (float*)d_out;

    k_fused<<<dim3(BB * NTT / NTB), dim3(512), 0, stream>>>(xc, yc, xt, W0, b0,
                                                            W1, b1, W2, b2, W3,
                                                            b3, out);
}

// Round 10
// 105.673 us; speedup vs baseline: 2.8947x; 2.8947x over previous
//
#include <hip/hip_runtime.h>
#include <math.h>

#define BB 8
#define NCC 1024
#define NTT 1024
#define HH 128
#define DYY 32
#define NTB 16                   // 512 blocks x 512 threads
#define LOG2E 1.44269504088896340736f

// r10: R4's compute structure + aliased 28.9KB LDS (2 blocks/CU), WITHOUT the
// r8 early-staging registers. r9 evidence: holding ty/tx (16 VGPR) across the
// L3/sigl region pushed peak past the (512,2) cap of 128 -> spill (VGPR=128,
// WRITE 426MB, 235us). Fix: load tiles 0,1 AFTER the sigl barrier, straight
// into the just-freed phase-2 arenas (live range ~4 instrs). One ~300cy L2
// stall per wave at phase-2 entry, once -- negligible vs spill.
//   phase 1:  HB[0,2112) RED[2112,2496) WCH[2496,6592)   (dead after sigl bar)
//   phase 2:  YCB[0,4096) XCB[4096,7168)                 (aliases phase 1)
//   epilogue: CMB[0,4224) SL[4224,4352)                  (barrier before dump)
//   SIGL[7168,7216) disjoint from all.
#define HB 0
#define RED 2112
#define WCH 2496
#define YCB 0
#define XCB 4096
#define SIGL 7168
#define SMEM_SZ 7216             // 28.9 KB
#define CMB 0
#define SL 4224
#define HSTRIDE 132              // mult of 4 (aligned b128); p vs p+8 = 2-way = free

// Wave-autonomous staging (r4-proven): W cols [16w,16w+16) and yc rows
// [128w,128w+128) are read ONLY by wave w -> wave-private LDS double-buffer,
// compiler-managed vmcnt/lgkmcnt, no barriers inside either pipeline.
// XCD swizzle (r6/r7-proven: FETCH 5.2->1.2MB): batch b pinned to XCD b.
// Phase 2 e-dedup: 2 exp/lane/tile, partner via shfl_xor(16).
// P<=0 (sig>0) => exp(P)<=1: no max subtraction.

#define ACC16(E, PTR)                                                          \
    do {                                                                       \
        const float4* yv_ = (const float4*)(PTR);                              \
        const float4 q0_ = yv_[0], q1_ = yv_[1], q2_ = yv_[2], q3_ = yv_[3];   \
        acc[0] = fmaf(E, q0_.x, acc[0]);                                       \
        acc[1] = fmaf(E, q0_.y, acc[1]);                                       \
        acc[2] = fmaf(E, q0_.z, acc[2]);                                       \
        acc[3] = fmaf(E, q0_.w, acc[3]);                                       \
        acc[4] = fmaf(E, q1_.x, acc[4]);                                       \
        acc[5] = fmaf(E, q1_.y, acc[5]);                                       \
        acc[6] = fmaf(E, q1_.z, acc[6]);                                       \
        acc[7] = fmaf(E, q1_.w, acc[7]);                                       \
        acc[8] = fmaf(E, q2_.x, acc[8]);                                       \
        acc[9] = fmaf(E, q2_.y, acc[9]);                                       \
        acc[10] = fmaf(E, q2_.z, acc[10]);                                     \
        acc[11] = fmaf(E, q2_.w, acc[11]);                                     \
        acc[12] = fmaf(E, q3_.x, acc[12]);                                     \
        acc[13] = fmaf(E, q3_.y, acc[13]);                                     \
        acc[14] = fmaf(E, q3_.z, acc[14]);                                     \
        acc[15] = fmaf(E, q3_.w, acc[15]);                                     \
    } while (0)

__global__ __launch_bounds__(512, 2) void k_fused(const float* __restrict__ xc,
                                                  const float* __restrict__ yc,
                                                  const float* __restrict__ xt,
                                                  const float* __restrict__ W0,
                                                  const float* __restrict__ b0,
                                                  const float* __restrict__ W1,
                                                  const float* __restrict__ b1,
                                                  const float* __restrict__ W2,
                                                  const float* __restrict__ b2,
                                                  const float* __restrict__ W3,
                                                  const float* __restrict__ b3,
                                                  float* __restrict__ out) {
    const int tid = threadIdx.x;
    const int phys = blockIdx.x;
    const int bid = (phys & 7) * 64 + (phys >> 3);   // XCD swizzle: batch<->XCD
    const int t0 = bid * NTB;
    const int b = bid >> 6;              // 64 blocks per batch
    const int wv = tid >> 6;             // wave 0..7
    const int lane = tid & 63;

    __shared__ float smem[SMEM_SZ];

    const float4* __restrict__ ycG4 = (const float4*)(yc + (size_t)b * NCC * DYY);
    const float4* __restrict__ xcG4 = (const float4*)(xc + (size_t)b * NCC * 3);

    float* ycw = smem + YCB + wv * 512;  // wave-private: 2 bufs x 256 floats
    float* xcw = smem + XCB + wv * 384;  // wave-private: 128 rows x 3
    const int ybase = wv * 1024;         // f4 index of wave's first yc row

    // ================= phase 1: MLP (r4 structure, proven) =================
    const int jg = tid >> 4;             // 0..31 col-group (4 cols)
    const int p = tid & 15;              // 0..15 point
    const int j0 = jg * 4;
    const int jl4 = (jg & 3) * 4;        // col offset within the wave's W slice
    float* hrow = smem + HB + p * HSTRIDE;

    {
        const float* xr = xt + (size_t)(t0 + p) * 3;
        const float x0 = xr[0], x1 = xr[1], x2 = xr[2];
        const float4* W0v = (const float4*)W0;
        const float4 w0a = W0v[jg], w0b = W0v[32 + jg], w0c = W0v[64 + jg];
        const float4 bb0 = ((const float4*)b0)[jg];
        float4 h0;
        h0.x = fmaxf(fmaf(x0, w0a.x, fmaf(x1, w0b.x, fmaf(x2, w0c.x, bb0.x))), 0.f);
        h0.y = fmaxf(fmaf(x0, w0a.y, fmaf(x1, w0b.y, fmaf(x2, w0c.y, bb0.y))), 0.f);
        h0.z = fmaxf(fmaf(x0, w0a.z, fmaf(x1, w0b.z, fmaf(x2, w0c.z, bb0.z))), 0.f);
        h0.w = fmaxf(fmaf(x0, w0a.w, fmaf(x1, w0b.w, fmaf(x2, w0c.w, bb0.w))), 0.f);
        *(float4*)(hrow + j0) = h0;
    }

    const int gWb = (lane >> 2) * 32 + wv * 4 + (lane & 3);
    float* wwb = smem + WCH + wv * 512;
    const float4* __restrict__ W1v = (const float4*)W1;
    const float4* __restrict__ W2v = (const float4*)W2;

    float4 wA0 = W1v[gWb], wA1 = W1v[gWb + 512];
    __syncthreads();                     // h(L0) visible

    auto run_layer = [&](const float4* __restrict__ Wv, const float4 bi,
                         float4 r0, float4 r1) -> float4 {
        float a0 = bi.x, a1 = bi.y, a2 = bi.z, a3 = bi.w;
        ((float4*)wwb)[lane] = r0;
        float4 wcur = r1;
#pragma unroll
        for (int c = 0; c < 8; ++c) {
            float4 wnext;
            if (c < 6) wnext = Wv[gWb + (c + 2) * 512];
            if (c < 7) ((float4*)(wwb + ((c + 1) & 1) * 256))[lane] = wcur;
            const float* wbc = wwb + (c & 1) * 256;
#pragma unroll
            for (int q = 0; q < 4; ++q) {
                const float4 ch = *(const float4*)(hrow + c * 16 + q * 4);
                const float4 k0 = *(const float4*)(wbc + (q * 4 + 0) * 16 + jl4);
                const float4 k1 = *(const float4*)(wbc + (q * 4 + 1) * 16 + jl4);
                const float4 k2 = *(const float4*)(wbc + (q * 4 + 2) * 16 + jl4);
                const float4 k3 = *(const float4*)(wbc + (q * 4 + 3) * 16 + jl4);
                a0 = fmaf(ch.x, k0.x, a0);
                a1 = fmaf(ch.x, k0.y, a1);
                a2 = fmaf(ch.x, k0.z, a2);
                a3 = fmaf(ch.x, k0.w, a3);
                a0 = fmaf(ch.y, k1.x, a0);
                a1 = fmaf(ch.y, k1.y, a1);
                a2 = fmaf(ch.y, k1.z, a2);
                a3 = fmaf(ch.y, k1.w, a3);
                a0 = fmaf(ch.z, k2.x, a0);
                a1 = fmaf(ch.z, k2.y, a1);
                a2 = fmaf(ch.z, k2.z, a2);
                a3 = fmaf(ch.z, k2.w, a3);
                a0 = fmaf(ch.w, k3.x, a0);
                a1 = fmaf(ch.w, k3.y, a1);
                a2 = fmaf(ch.w, k3.z, a2);
                a3 = fmaf(ch.w, k3.w, a3);
            }
            wcur = wnext;
        }
        float4 r;
        r.x = fmaxf(a0, 0.f);
        r.y = fmaxf(a1, 0.f);
        r.z = fmaxf(a2, 0.f);
        r.w = fmaxf(a3, 0.f);
        return r;
    };

    float4 oL1 = run_layer(W1v, ((const float4*)b1)[jg], wA0, wA1);
    float4 wB0 = W2v[gWb], wB1 = W2v[gWb + 512];
    __syncthreads();                     // h(L0) reads done
    *(float4*)(hrow + j0) = oL1;
    __syncthreads();                     // h(L1) visible
    float4 oL2 = run_layer(W2v, ((const float4*)b2)[jg], wB0, wB1);

    {
        const float4* W3v = (const float4*)W3;
        const float4 wr0 = W3v[jg * 3 + 0];
        const float4 wr1 = W3v[jg * 3 + 1];
        const float4 wr2 = W3v[jg * 3 + 2];
        float p0 = oL2.x * wr0.x + oL2.y * wr0.w + oL2.z * wr1.z + oL2.w * wr2.y;
        float p1 = oL2.x * wr0.y + oL2.y * wr1.x + oL2.z * wr1.w + oL2.w * wr2.z;
        float p2 = oL2.x * wr0.z + oL2.y * wr1.y + oL2.z * wr2.x + oL2.w * wr2.w;
        p0 += __shfl_xor(p0, 16, 64);    // lane bits 4,5 = jg&3: reduce 4 jg
        p0 += __shfl_xor(p0, 32, 64);
        p1 += __shfl_xor(p1, 16, 64);
        p1 += __shfl_xor(p1, 32, 64);
        p2 += __shfl_xor(p2, 16, 64);
        p2 += __shfl_xor(p2, 32, 64);
        if (lane < 16) {                 // lane = p here
            smem[RED + wv * 48 + lane * 3 + 0] = p0;
            smem[RED + wv * 48 + lane * 3 + 1] = p1;
            smem[RED + wv * 48 + lane * 3 + 2] = p2;
        }
    }
    __syncthreads();
    if (tid < 48) {
        const int r = tid / 3, cix = tid - r * 3;
        float v = b3[cix];
#pragma unroll
        for (int g = 0; g < 8; ++g) v += smem[RED + g * 48 + r * 3 + cix];
        smem[SIGL + r * 3 + cix] = __expf(v) * LOG2E;
    }
    __syncthreads();                     // sigl ready; phase-1 arenas DEAD

    // ---- stage tiles 0,1 NOW (arenas just freed; short live range) ----
    {
        float4 ty0 = ycG4[ybase + lane];
        float4 ty1 = ycG4[ybase + 64 + lane];
        ((float4*)ycw)[lane] = ty0;
        ((float4*)(ycw + 256))[lane] = ty1;
        if (lane < 48) {
            float4 tx0 = xcG4[wv * 96 + lane];
            float4 tx1 = xcG4[wv * 96 + 48 + lane];
            ((float4*)xcw)[lane] = tx0;
            ((float4*)xcw)[lane + 48] = tx1;
        }
    }

    // ========== phase 2: attention, wave-autonomous, barrier-free ==========
    const int tl = lane & 15;            // target within block
    const int dg = (lane >> 4) & 1;      // d-half
    const int ns = lane >> 5;            // n-half within the wave's 8-row tile
    const int dg16 = dg * 16;
    const int rown = ns * 4 + dg * 2;        // own e rows
    const int rowo = ns * 4 + 2 - dg * 2;    // partner e rows (via shfl)

    const float s0 = smem[SIGL + tl * 3 + 0];
    const float s1 = smem[SIGL + tl * 3 + 1];
    const float s2 = smem[SIGL + tl * 3 + 2];
    const float* ar = xt + (size_t)(t0 + tl) * 3;
    const float a0 = ar[0], a1 = ar[1], a2 = ar[2];

    float acc[16];
#pragma unroll
    for (int i = 0; i < 16; ++i) acc[i] = 0.f;
    float l = 0.f;

#pragma unroll 2
    for (int t = 0; t < 16; ++t) {
        float4 ynext;
        if (t < 14) ynext = ycG4[ybase + (t + 2) * 64 + lane];   // issue early
        const float* yb = ycw + (t & 1) * 256;
        const float* xb = xcw + t * 24;

        float d0 = xb[rown * 3 + 0] - a0;
        float d1 = xb[rown * 3 + 1] - a1;
        float d2 = xb[rown * 3 + 2] - a2;
        float pp = fmaf(s0, d0 * d0, fmaf(s1, d1 * d1, s2 * (d2 * d2)));
        const float eo0 = exp2f(-pp);
        d0 = xb[rown * 3 + 3] - a0;
        d1 = xb[rown * 3 + 4] - a1;
        d2 = xb[rown * 3 + 5] - a2;
        pp = fmaf(s0, d0 * d0, fmaf(s1, d1 * d1, s2 * (d2 * d2)));
        const float eo1 = exp2f(-pp);
        l += eo0 + eo1;
        const float ex0 = __shfl_xor(eo0, 16, 64);   // partner's rows
        const float ex1 = __shfl_xor(eo1, 16, 64);

        ACC16(eo0, yb + rown * 32 + dg16);
        ACC16(eo1, yb + (rown + 1) * 32 + dg16);
        ACC16(ex0, yb + rowo * 32 + dg16);
        ACC16(ex1, yb + (rowo + 1) * 32 + dg16);

        if (t < 14)                      // buf just freed; same-wave DS order
            ((float4*)(ycw + (t & 1) * 256))[lane] = ynext;
    }

    // ---- merge dg-pair l, merge ns pairs ----
    l += __shfl_xor(l, 16, 64);          // l was dg-split by the e-dedup
#pragma unroll
    for (int i = 0; i < 16; ++i) acc[i] += __shfl_xor(acc[i], 32, 64);
    l += __shfl_xor(l, 32, 64);

    __syncthreads();                     // all phase-2 LDS reads done: CMB may
                                         // now overwrite YCB/XCB
    if (ns == 0) {
#pragma unroll
        for (int i = 0; i < 16; ++i)
            smem[CMB + (wv * 16 + tl) * 33 + dg16 + i] = acc[i];
        if (dg == 0) smem[SL + wv * 16 + tl] = l;
    }
    __syncthreads();
    {
        const int rtl = tid >> 5, d = tid & 31;   // each thread owns one output
        float ssum = 0.f, lsum = 0.f;
#pragma unroll
        for (int ww = 0; ww < 8; ++ww) {
            ssum += smem[CMB + (ww * 16 + rtl) * 33 + d];
            lsum += smem[SL + ww * 16 + rtl];
        }
        out[(size_t)(t0 + rtl) * DYY + d] = ssum / lsum;
    }
}

extern "C" void kernel_launch(void* const* d_in, const int* in_sizes, int n_in,
                              void* d_out, int out_size, void* d_ws, size_t ws_size,
                              hipStream_t stream) {
    const float* xc = (const float*)d_in[0];
    const float* yc = (const float*)d_in[1];
    const float* xt = (const float*)d_in[2];
    const float* W0 = (const float*)d_in[3];
    const float* b0 = (const float*)d_in[4];
    const float* W1 = (const float*)d_in[5];
    const float* b1 = (const float*)d_in[6];
    const float* W2 = (const float*)d_in[7];
    const float* b2 = (const float*)d_in[8];
    const float* W3 = (const float*)d_in[9];
    const float* b3 = (const float*)d_in[10];
    float* out = (float*)d_out;

    k_fused<<<dim3(BB * NTT / NTB), dim3(512), 0, stream>>>(xc, yc, xt, W0, b0,
                                                            W1, b1, W2, b2, W3,
                                                            b3, out);
}

// Round 11
// 91.899 us; speedup vs baseline: 3.3285x; 1.1499x over previous
//
#include <hip/hip_runtime.h>
#include <math.h>

#define BB 8
#define NCC 1024
#define NTT 1024
#define HH 128
#define DYY 32
#define NTB 16                   // 512 blocks x 512 threads
#define LOG2E 1.44269504088896340736f

typedef _Float16 half8 __attribute__((ext_vector_type(8)));
typedef float f32x4 __attribute__((ext_vector_type(4)));

// r11: phase-2 einsum moved to MFMA (f16 in, f32 accum). Evidence: occupancy
// A/B closed (R1 31% / R4 19% / R10 19% all ~41-43us, VALUBusy 33-36%) -> the
// plateau is the VALU work itself. The einsum is 537 MFLOP with K=1024 ->
// matrix-core shaped; MfmaUtil was 0 all session.
// GEMM per wave: D(16t x 32d) += ET(16t x 32n-chunk) * Y(32n x 32d), 4 chunks.
// Fragment layouts (m89-verified C/D + documented A/B conventions):
//   A[m][k]: m=lane&15, k=8*(lane>>4)+i  (E: m=target, k=context)
//   B[k][n]: n=lane&15, k=8*(lane>>4)+i  (Y: n=d-col -> ds_read_b128 from ycT)
//   D[m][n]: n=lane&15, m=4*(lane>>4)+reg
// l (denominator) sums the SAME f16-rounded E in fp32 -> rounding acts as a
// reweighting (~1e-4), not a numerator/denominator mismatch.
//
// LDS arenas (time-aliased, 8240 floats = 32.96 KB):
//   phase 1:  HB[0,2112) RED[2112,2496) WCH[2496,6592)   (dead after sigl bar)
//   phase 2:  per-wave arena wv*1024..+1024: ycT [32][40] f16 (640 f) +
//             xcw [128][3] f32 (384 f)                    (aliases phase 1)
//   epilogue: CMB[0,4224) SL[4224,4352)                   (barrier before dump)
//   SIGL[8192,8240) disjoint from all.
#define HB 0
#define RED 2112
#define WCH 2496
#define SIGL 8192
#define SMEM_SZ 8240
#define CMB 0
#define SL 4224
#define HSTRIDE 132

__global__ __launch_bounds__(512, 2) void k_fused(const float* __restrict__ xc,
                                                  const float* __restrict__ yc,
                                                  const float* __restrict__ xt,
                                                  const float* __restrict__ W0,
                                                  const float* __restrict__ b0,
                                                  const float* __restrict__ W1,
                                                  const float* __restrict__ b1,
                                                  const float* __restrict__ W2,
                                                  const float* __restrict__ b2,
                                                  const float* __restrict__ W3,
                                                  const float* __restrict__ b3,
                                                  float* __restrict__ out) {
    const int tid = threadIdx.x;
    const int phys = blockIdx.x;
    const int bid = (phys & 7) * 64 + (phys >> 3);   // XCD swizzle (FETCH 1.2MB proven)
    const int t0 = bid * NTB;
    const int b = bid >> 6;              // 64 blocks per batch
    const int wv = tid >> 6;             // wave 0..7
    const int lane = tid & 63;

    __shared__ float smem[SMEM_SZ];

    const float4* __restrict__ xcG4 = (const float4*)(xc + (size_t)b * NCC * 3);

    // ================= phase 1: MLP (r10 structure, proven, untouched) ======
    const int jg = tid >> 4;
    const int p = tid & 15;
    const int j0 = jg * 4;
    const int jl4 = (jg & 3) * 4;
    float* hrow = smem + HB + p * HSTRIDE;

    {
        const float* xr = xt + (size_t)(t0 + p) * 3;
        const float x0 = xr[0], x1 = xr[1], x2 = xr[2];
        const float4* W0v = (const float4*)W0;
        const float4 w0a = W0v[jg], w0b = W0v[32 + jg], w0c = W0v[64 + jg];
        const float4 bb0 = ((const float4*)b0)[jg];
        float4 h0;
        h0.x = fmaxf(fmaf(x0, w0a.x, fmaf(x1, w0b.x, fmaf(x2, w0c.x, bb0.x))), 0.f);
        h0.y = fmaxf(fmaf(x0, w0a.y, fmaf(x1, w0b.y, fmaf(x2, w0c.y, bb0.y))), 0.f);
        h0.z = fmaxf(fmaf(x0, w0a.z, fmaf(x1, w0b.z, fmaf(x2, w0c.z, bb0.z))), 0.f);
        h0.w = fmaxf(fmaf(x0, w0a.w, fmaf(x1, w0b.w, fmaf(x2, w0c.w, bb0.w))), 0.f);
        *(float4*)(hrow + j0) = h0;
    }

    const int gWb = (lane >> 2) * 32 + wv * 4 + (lane & 3);
    float* wwb = smem + WCH + wv * 512;
    const float4* __restrict__ W1v = (const float4*)W1;
    const float4* __restrict__ W2v = (const float4*)W2;

    float4 wA0 = W1v[gWb], wA1 = W1v[gWb + 512];
    __syncthreads();                     // h(L0) visible

    auto run_layer = [&](const float4* __restrict__ Wv, const float4 bi,
                         float4 r0, float4 r1) -> float4 {
        float a0 = bi.x, a1 = bi.y, a2 = bi.z, a3 = bi.w;
        ((float4*)wwb)[lane] = r0;
        float4 wcur = r1;
#pragma unroll
        for (int c = 0; c < 8; ++c) {
            float4 wnext;
            if (c < 6) wnext = Wv[gWb + (c + 2) * 512];
            if (c < 7) ((float4*)(wwb + ((c + 1) & 1) * 256))[lane] = wcur;
            const float* wbc = wwb + (c & 1) * 256;
#pragma unroll
            for (int q = 0; q < 4; ++q) {
                const float4 ch = *(const float4*)(hrow + c * 16 + q * 4);
                const float4 k0 = *(const float4*)(wbc + (q * 4 + 0) * 16 + jl4);
                const float4 k1 = *(const float4*)(wbc + (q * 4 + 1) * 16 + jl4);
                const float4 k2 = *(const float4*)(wbc + (q * 4 + 2) * 16 + jl4);
                const float4 k3 = *(const float4*)(wbc + (q * 4 + 3) * 16 + jl4);
                a0 = fmaf(ch.x, k0.x, a0);
                a1 = fmaf(ch.x, k0.y, a1);
                a2 = fmaf(ch.x, k0.z, a2);
                a3 = fmaf(ch.x, k0.w, a3);
                a0 = fmaf(ch.y, k1.x, a0);
                a1 = fmaf(ch.y, k1.y, a1);
                a2 = fmaf(ch.y, k1.z, a2);
                a3 = fmaf(ch.y, k1.w, a3);
                a0 = fmaf(ch.z, k2.x, a0);
                a1 = fmaf(ch.z, k2.y, a1);
                a2 = fmaf(ch.z, k2.z, a2);
                a3 = fmaf(ch.z, k2.w, a3);
                a0 = fmaf(ch.w, k3.x, a0);
                a1 = fmaf(ch.w, k3.y, a1);
                a2 = fmaf(ch.w, k3.z, a2);
                a3 = fmaf(ch.w, k3.w, a3);
            }
            wcur = wnext;
        }
        float4 r;
        r.x = fmaxf(a0, 0.f);
        r.y = fmaxf(a1, 0.f);
        r.z = fmaxf(a2, 0.f);
        r.w = fmaxf(a3, 0.f);
        return r;
    };

    float4 oL1 = run_layer(W1v, ((const float4*)b1)[jg], wA0, wA1);
    float4 wB0 = W2v[gWb], wB1 = W2v[gWb + 512];
    __syncthreads();                     // h(L0) reads done
    *(float4*)(hrow + j0) = oL1;
    __syncthreads();                     // h(L1) visible
    float4 oL2 = run_layer(W2v, ((const float4*)b2)[jg], wB0, wB1);

    {
        const float4* W3v = (const float4*)W3;
        const float4 wr0 = W3v[jg * 3 + 0];
        const float4 wr1 = W3v[jg * 3 + 1];
        const float4 wr2 = W3v[jg * 3 + 2];
        float p0 = oL2.x * wr0.x + oL2.y * wr0.w + oL2.z * wr1.z + oL2.w * wr2.y;
        float p1 = oL2.x * wr0.y + oL2.y * wr1.x + oL2.z * wr1.w + oL2.w * wr2.z;
        float p2 = oL2.x * wr0.z + oL2.y * wr1.y + oL2.z * wr2.x + oL2.w * wr2.w;
        p0 += __shfl_xor(p0, 16, 64);
        p0 += __shfl_xor(p0, 32, 64);
        p1 += __shfl_xor(p1, 16, 64);
        p1 += __shfl_xor(p1, 32, 64);
        p2 += __shfl_xor(p2, 16, 64);
        p2 += __shfl_xor(p2, 32, 64);
        if (lane < 16) {
            smem[RED + wv * 48 + lane * 3 + 0] = p0;
            smem[RED + wv * 48 + lane * 3 + 1] = p1;
            smem[RED + wv * 48 + lane * 3 + 2] = p2;
        }
    }
    __syncthreads();
    if (tid < 48) {
        const int r = tid / 3, cix = tid - r * 3;
        float v = b3[cix];
#pragma unroll
        for (int g2 = 0; g2 < 8; ++g2) v += smem[RED + g2 * 48 + r * 3 + cix];
        smem[SIGL + r * 3 + cix] = __expf(v) * LOG2E;
    }
    __syncthreads();                     // sigl ready; phase-1 arenas DEAD

    // ========== phase 2: E on VALU, einsum on MFMA, wave-autonomous ==========
    const int tl = lane & 15;            // target (= MFMA A m-index)
    const int g = lane >> 4;             // k-group 0..3
    const int sd = lane & 31;            // staging: d column
    const int snr = lane >> 5;           // staging: n-half

    const float s0 = smem[SIGL + tl * 3 + 0];
    const float s1 = smem[SIGL + tl * 3 + 1];
    const float s2 = smem[SIGL + tl * 3 + 2];
    const float* ar = xt + (size_t)(t0 + tl) * 3;
    const float a0 = ar[0], a1 = ar[1], a2 = ar[2];

    float* warena = smem + wv * 1024;    // wave-private
    _Float16* ycT = (_Float16*)warena;   // [32 d][40 n-stride] f16 (one 32-n chunk)
    float* xcw = warena + 640;           // [128][3] f32

    if (lane < 48) {                     // stage wave's xc slice
        float4 tx0 = xcG4[wv * 96 + lane];
        float4 tx1 = xcG4[wv * 96 + 48 + lane];
        ((float4*)xcw)[lane] = tx0;
        ((float4*)xcw)[lane + 48] = tx1;
    }

    // ycT staging: lane gathers column sd, 16 rows/chunk (2 halves x 8), cvt
    // f16, one ds_write_b128 per 8-run. Coalescing: per load instr the 32 d
    // lanes hit one 128B row segment x2 snr.
    const float* ycol = yc + (size_t)b * NCC * DYY + (size_t)(wv * 128) * DYY + sd;
    float ld[16];
#define YLOAD(C)                                                               \
    _Pragma("unroll") for (int q = 0; q < 16; ++q)                             \
        ld[q] = ycol[(size_t)((C) * 32 + (q >> 3) * 16 + snr * 8 + (q & 7)) * DYY];
#define YWRITE()                                                               \
    do {                                                                       \
        _Pragma("unroll") for (int r = 0; r < 2; ++r) {                        \
            half8 pk;                                                          \
            _Pragma("unroll") for (int j = 0; j < 8; ++j)                      \
                pk[j] = (_Float16)ld[r * 8 + j];                               \
            *(half8*)(ycT + sd * 40 + r * 16 + snr * 8) = pk;                  \
        }                                                                      \
    } while (0)

    YLOAD(0);
    YWRITE();

    f32x4 acc0 = {0.f, 0.f, 0.f, 0.f};
    f32x4 acc1 = {0.f, 0.f, 0.f, 0.f};
    float l = 0.f;

#pragma unroll
    for (int c = 0; c < 4; ++c) {
        if (c < 3) YLOAD(c + 1);         // prefetch next chunk into regs

        float xv[24];                    // this lane's 8 xc rows (static idx)
        {
            const float4* xr4 = (const float4*)(xcw + (c * 32 + g * 8) * 3);
#pragma unroll
            for (int q = 0; q < 6; ++q) *(float4*)(xv + q * 4) = xr4[q];
        }
        half8 af;                        // A-frag: E[t=tl][k=8g+i]
#pragma unroll
        for (int i = 0; i < 8; ++i) {
            const float d0 = xv[i * 3 + 0] - a0;
            const float d1 = xv[i * 3 + 1] - a1;
            const float d2 = xv[i * 3 + 2] - a2;
            const float pp = fmaf(s0, d0 * d0, fmaf(s1, d1 * d1, s2 * (d2 * d2)));
            const _Float16 eh = (_Float16)exp2f(-pp);
            af[i] = eh;
            l += (float)eh;              // denominator from the SAME f16 E
        }
        // B-frags: ycT[d = 16h + tl][n-run 8g..8g+7] (aligned b128)
        const half8 bf0 = *(const half8*)(ycT + tl * 40 + g * 8);
        const half8 bf1 = *(const half8*)(ycT + (16 + tl) * 40 + g * 8);
        acc0 = __builtin_amdgcn_mfma_f32_16x16x32_f16(af, bf0, acc0, 0, 0, 0);
        acc1 = __builtin_amdgcn_mfma_f32_16x16x32_f16(af, bf1, acc1, 0, 0, 0);

        if (c < 3) YWRITE();             // same-wave in-order DS: after reads
    }

    // l: reduce over the 4 k-groups -> full 128-n sum per target
    l += __shfl_xor(l, 16, 64);
    l += __shfl_xor(l, 32, 64);

    __syncthreads();                     // phase-2 arena reads done; CMB aliases
    // D[m=t][n=d]: t = 4g+reg, d = 16h + tl
#pragma unroll
    for (int r = 0; r < 4; ++r) {
        smem[CMB + wv * 528 + (g * 4 + r) * 33 + tl] = acc0[r];
        smem[CMB + wv * 528 + (g * 4 + r) * 33 + 16 + tl] = acc1[r];
    }
    if (lane < 16) smem[SL + wv * 16 + lane] = l;
    __syncthreads();
    {
        const int t = tid >> 5, d = tid & 31;   // each thread owns one output
        float s = 0.f, ls = 0.f;
#pragma unroll
        for (int w = 0; w < 8; ++w) {
            s += smem[CMB + w * 528 + t * 33 + d];
            ls += smem[SL + w * 16 + t];
        }
        out[(size_t)(t0 + t) * DYY + d] = s / ls;
    }
#undef YLOAD
#undef YWRITE
}

extern "C" void kernel_launch(void* const* d_in, const int* in_sizes, int n_in,
                              void* d_out, int out_size, void* d_ws, size_t ws_size,
                              hipStream_t stream) {
    const float* xc = (const float*)d_in[0];
    const float* yc = (const float*)d_in[1];
    const float* xt = (const float*)d_in[2];
    const float* W0 = (const float*)d_in[3];
    const float* b0 = (const float*)d_in[4];
    const float* W1 = (const float*)d_in[5];
    const float* b1 = (const float*)d_in[6];
    const float* W2 = (const float*)d_in[7];
    const float* b2 = (const float*)d_in[8];
    const float* W3 = (const float*)d_in[9];
    const float* b3 = (const float*)d_in[10];
    float* out = (float*)d_out;

    k_fused<<<dim3(BB * NTT / NTB), dim3(512), 0, stream>>>(xc, yc, xt, W0, b0,
                                                            W1, b1, W2, b2, W3,
                                                            b3, out);
}

// Round 12
// 85.537 us; speedup vs baseline: 3.5761x; 1.0744x over previous
//
#include <hip/hip_runtime.h>
#include <math.h>

#define BB 8
#define NCC 1024
#define NTT 1024
#define HH 128
#define DYY 32
#define NTB 16                   // 512 blocks x 512 threads
#define LOG2E 1.44269504088896340736f

typedef _Float16 half8 __attribute__((ext_vector_type(8)));
typedef float f32x4 __attribute__((ext_vector_type(4)));

// r12: phase-1 L1/L2 moved to MFMA with f16x2 split (error ~2^-22/layer --
// invisible vs the existing 2^-8 absmax from phase-2's f16 E). r11 post-mortem:
// kernel ~27us, phase 1 ~19-20us of which most is its 336 ds_read_b128/wave
// W-streaming pipeline (the DS-pipe serialization that capped r0-r10).
// New per-layer per-wave: D(16p x 16j) = h(16p x 128k) @ W cols, 4 K=32 chunks
// x 3 MFMAs (f0f0'+f0f1'+f1f0'). B-frag (W[8g+i][j0+tl]) gathered DIRECT from
// global -- 64B-coalesced per 16-lane cluster, W is L2-hot (shared by 64
// blocks/XCD). Zero W LDS. DS/wave/layer: 336 -> ~25.
// Fragment layouts hardware-confirmed by r11 (passed with exact-f16 absmax):
//   A[m][k]: m=lane&15, k=8*(lane>>4)+i    B[k][n]: n=lane&15, k=8*(lane>>4)+i
//   D[m][n]: n=lane&15, m=4*(lane>>4)+reg
//
// LDS arenas (time-aliased, 8240 floats = 32.96 KB):
//   phase 1:  HB[0,2112) RED[2112,2496)                  (dead after sigl bar)
//   phase 2:  per-wave arena wv*1024..+1024: ycT [32][40] f16 + xcw [128][3]
//   epilogue: CMB[0,4224) SL[4224,4352)                  (barrier before dump)
//   SIGL[8192,8240) disjoint from all.
#define HB 0
#define RED 2112
#define SIGL 8192
#define SMEM_SZ 8240
#define CMB 0
#define SL 4224
#define HSTRIDE 132

__global__ __launch_bounds__(512, 2) void k_fused(const float* __restrict__ xc,
                                                  const float* __restrict__ yc,
                                                  const float* __restrict__ xt,
                                                  const float* __restrict__ W0,
                                                  const float* __restrict__ b0,
                                                  const float* __restrict__ W1,
                                                  const float* __restrict__ b1,
                                                  const float* __restrict__ W2,
                                                  const float* __restrict__ b2,
                                                  const float* __restrict__ W3,
                                                  const float* __restrict__ b3,
                                                  float* __restrict__ out) {
    const int tid = threadIdx.x;
    const int phys = blockIdx.x;
    const int bid = (phys & 7) * 64 + (phys >> 3);   // XCD swizzle (FETCH 1.2MB proven)
    const int t0 = bid * NTB;
    const int b = bid >> 6;              // 64 blocks per batch
    const int wv = tid >> 6;             // wave 0..7
    const int lane = tid & 63;

    __shared__ float smem[SMEM_SZ];

    const float4* __restrict__ xcG4 = (const float4*)(xc + (size_t)b * NCC * 3);

    // ================= phase 1: MLP =================
    const int jg = tid >> 4;             // L0/L3 mapping (unchanged)
    const int p = tid & 15;
    const int j0 = jg * 4;
    float* hrow = smem + HB + p * HSTRIDE;

    // ---- L0 (VALU, cheap) ----
    {
        const float* xr = xt + (size_t)(t0 + p) * 3;
        const float x0 = xr[0], x1 = xr[1], x2 = xr[2];
        const float4* W0v = (const float4*)W0;
        const float4 w0a = W0v[jg], w0b = W0v[32 + jg], w0c = W0v[64 + jg];
        const float4 bb0 = ((const float4*)b0)[jg];
        float4 h0;
        h0.x = fmaxf(fmaf(x0, w0a.x, fmaf(x1, w0b.x, fmaf(x2, w0c.x, bb0.x))), 0.f);
        h0.y = fmaxf(fmaf(x0, w0a.y, fmaf(x1, w0b.y, fmaf(x2, w0c.y, bb0.y))), 0.f);
        h0.z = fmaxf(fmaf(x0, w0a.z, fmaf(x1, w0b.z, fmaf(x2, w0c.z, bb0.z))), 0.f);
        h0.w = fmaxf(fmaf(x0, w0a.w, fmaf(x1, w0b.w, fmaf(x2, w0c.w, bb0.w))), 0.f);
        *(float4*)(hrow + j0) = h0;
    }
    __syncthreads();                     // h(L0) visible

    // ---- L1, L2: MFMA f16x2, W gathered from global ----
    {
        const int mtl = lane & 15;       // A m-index (point) AND B n-index
        const int mg = lane >> 4;        // k-group 0..3
        const int jcol = wv * 16 + mtl;  // this lane's output column

#pragma unroll
        for (int l = 0; l < 2; ++l) {
            const float* __restrict__ Wg = (l == 0) ? W1 : W2;
            const float* __restrict__ bi = (l == 0) ? b1 : b2;
            f32x4 dac;
            {
                const float bj = bi[jcol];
                dac[0] = bj; dac[1] = bj; dac[2] = bj; dac[3] = bj;
            }
            float w[8];
#pragma unroll
            for (int i = 0; i < 8; ++i) w[i] = Wg[(mg * 8 + i) * HH + jcol];
#pragma unroll
            for (int c = 0; c < 4; ++c) {
                float wn[8];
                if (c < 3) {             // prefetch next chunk's W column slice
#pragma unroll
                    for (int i = 0; i < 8; ++i)
                        wn[i] = Wg[((c + 1) * 32 + mg * 8 + i) * HH + jcol];
                }
                float hv[8];             // A: h[point=mtl][k=32c+8mg+i]
                *(float4*)hv =
                    *(const float4*)(smem + HB + mtl * HSTRIDE + c * 32 + mg * 8);
                *(float4*)(hv + 4) =
                    *(const float4*)(smem + HB + mtl * HSTRIDE + c * 32 + mg * 8 + 4);
                half8 a0, a1, bf0, bf1;
#pragma unroll
                for (int i = 0; i < 8; ++i) {
                    const _Float16 ah = (_Float16)hv[i];
                    a0[i] = ah;
                    a1[i] = (_Float16)(hv[i] - (float)ah);
                    const _Float16 wh = (_Float16)w[i];
                    bf0[i] = wh;
                    bf1[i] = (_Float16)(w[i] - (float)wh);
                }
                dac = __builtin_amdgcn_mfma_f32_16x16x32_f16(a0, bf0, dac, 0, 0, 0);
                dac = __builtin_amdgcn_mfma_f32_16x16x32_f16(a0, bf1, dac, 0, 0, 0);
                dac = __builtin_amdgcn_mfma_f32_16x16x32_f16(a1, bf0, dac, 0, 0, 0);
                if (c < 3) {
#pragma unroll
                    for (int i = 0; i < 8; ++i) w[i] = wn[i];
                }
            }
            __syncthreads();             // all waves done reading h(prev)
#pragma unroll
            for (int r = 0; r < 4; ++r)  // D[m=4mg+r][n=mtl] -> h[point][jcol]
                smem[HB + (mg * 4 + r) * HSTRIDE + jcol] = fmaxf(dac[r], 0.f);
            __syncthreads();             // h(l) visible
        }
    }

    // ---- L3 + exp -> sig*log2e (original mapping, from LDS) ----
    {
        const float4 o4 = *(const float4*)(hrow + j0);   // h2[p][4jg..+4]
        const float4* W3v = (const float4*)W3;
        const float4 wr0 = W3v[jg * 3 + 0];
        const float4 wr1 = W3v[jg * 3 + 1];
        const float4 wr2 = W3v[jg * 3 + 2];
        float p0 = o4.x * wr0.x + o4.y * wr0.w + o4.z * wr1.z + o4.w * wr2.y;
        float p1 = o4.x * wr0.y + o4.y * wr1.x + o4.z * wr1.w + o4.w * wr2.z;
        float p2 = o4.x * wr0.z + o4.y * wr1.y + o4.z * wr2.x + o4.w * wr2.w;
        p0 += __shfl_xor(p0, 16, 64);
        p0 += __shfl_xor(p0, 32, 64);
        p1 += __shfl_xor(p1, 16, 64);
        p1 += __shfl_xor(p1, 32, 64);
        p2 += __shfl_xor(p2, 16, 64);
        p2 += __shfl_xor(p2, 32, 64);
        if (lane < 16) {
            smem[RED + wv * 48 + lane * 3 + 0] = p0;
            smem[RED + wv * 48 + lane * 3 + 1] = p1;
            smem[RED + wv * 48 + lane * 3 + 2] = p2;
        }
    }
    __syncthreads();
    if (tid < 48) {
        const int r = tid / 3, cix = tid - r * 3;
        float v = b3[cix];
#pragma unroll
        for (int g2 = 0; g2 < 8; ++g2) v += smem[RED + g2 * 48 + r * 3 + cix];
        smem[SIGL + r * 3 + cix] = __expf(v) * LOG2E;
    }
    __syncthreads();                     // sigl ready; phase-1 arenas DEAD

    // ========== phase 2: E on VALU, einsum on MFMA (r11, proven) ==========
    const int tl = lane & 15;            // target (= MFMA A m-index)
    const int g = lane >> 4;             // k-group 0..3
    const int sd = lane & 31;            // staging: d column
    const int snr = lane >> 5;           // staging: n-half

    const float s0 = smem[SIGL + tl * 3 + 0];
    const float s1 = smem[SIGL + tl * 3 + 1];
    const float s2 = smem[SIGL + tl * 3 + 2];
    const float* ar = xt + (size_t)(t0 + tl) * 3;
    const float a0 = ar[0], a1 = ar[1], a2 = ar[2];

    float* warena = smem + wv * 1024;    // wave-private
    _Float16* ycT = (_Float16*)warena;   // [32 d][40 n-stride] f16
    float* xcw = warena + 640;           // [128][3] f32

    if (lane < 48) {                     // stage wave's xc slice
        float4 tx0 = xcG4[wv * 96 + lane];
        float4 tx1 = xcG4[wv * 96 + 48 + lane];
        ((float4*)xcw)[lane] = tx0;
        ((float4*)xcw)[lane + 48] = tx1;
    }

    const float* ycol = yc + (size_t)b * NCC * DYY + (size_t)(wv * 128) * DYY + sd;
    float ld[16];
#define YLOAD(C)                                                               \
    _Pragma("unroll") for (int q = 0; q < 16; ++q)                             \
        ld[q] = ycol[(size_t)((C) * 32 + (q >> 3) * 16 + snr * 8 + (q & 7)) * DYY];
#define YWRITE()                                                               \
    do {                                                                       \
        _Pragma("unroll") for (int r = 0; r < 2; ++r) {                        \
            half8 pk;                                                          \
            _Pragma("unroll") for (int j = 0; j < 8; ++j)                      \
                pk[j] = (_Float16)ld[r * 8 + j];                               \
            *(half8*)(ycT + sd * 40 + r * 16 + snr * 8) = pk;                  \
        }                                                                      \
    } while (0)

    YLOAD(0);
    YWRITE();

    f32x4 acc0 = {0.f, 0.f, 0.f, 0.f};
    f32x4 acc1 = {0.f, 0.f, 0.f, 0.f};
    float l = 0.f;

#pragma unroll
    for (int c = 0; c < 4; ++c) {
        if (c < 3) YLOAD(c + 1);         // prefetch next chunk into regs

        float xv[24];                    // this lane's 8 xc rows (static idx)
        {
            const float4* xr4 = (const float4*)(xcw + (c * 32 + g * 8) * 3);
#pragma unroll
            for (int q = 0; q < 6; ++q) *(float4*)(xv + q * 4) = xr4[q];
        }
        half8 af;                        // A-frag: E[t=tl][k=8g+i]
#pragma unroll
        for (int i = 0; i < 8; ++i) {
            const float d0 = xv[i * 3 + 0] - a0;
            const float d1 = xv[i * 3 + 1] - a1;
            const float d2 = xv[i * 3 + 2] - a2;
            const float pp = fmaf(s0, d0 * d0, fmaf(s1, d1 * d1, s2 * (d2 * d2)));
            const _Float16 eh = (_Float16)exp2f(-pp);
            af[i] = eh;
            l += (float)eh;              // denominator from the SAME f16 E
        }
        const half8 bf0 = *(const half8*)(ycT + tl * 40 + g * 8);
        const half8 bf1 = *(const half8*)(ycT + (16 + tl) * 40 + g * 8);
        acc0 = __builtin_amdgcn_mfma_f32_16x16x32_f16(af, bf0, acc0, 0, 0, 0);
        acc1 = __builtin_amdgcn_mfma_f32_16x16x32_f16(af, bf1, acc1, 0, 0, 0);

        if (c < 3) YWRITE();             // same-wave in-order DS: after reads
    }

    // l: reduce over the 4 k-groups -> full 128-n sum per target
    l += __shfl_xor(l, 16, 64);
    l += __shfl_xor(l, 32, 64);

    __syncthreads();                     // phase-2 arena reads done; CMB aliases
#pragma unroll
    for (int r = 0; r < 4; ++r) {
        smem[CMB + wv * 528 + (g * 4 + r) * 33 + tl] = acc0[r];
        smem[CMB + wv * 528 + (g * 4 + r) * 33 + 16 + tl] = acc1[r];
    }
    if (lane < 16) smem[SL + wv * 16 + lane] = l;
    __syncthreads();
    {
        const int t = tid >> 5, d = tid & 31;   // each thread owns one output
        float s = 0.f, ls = 0.f;
#pragma unroll
        for (int w = 0; w < 8; ++w) {
            s += smem[CMB + w * 528 + t * 33 + d];
            ls += smem[SL + w * 16 + t];
        }
        out[(size_t)(t0 + t) * DYY + d] = s / ls;
    }
#undef YLOAD
#undef YWRITE
}

extern "C" void kernel_launch(void* const* d_in, const int* in_sizes, int n_in,
                              void* d_out, int out_size, void* d_ws, size_t ws_size,
                              hipStream_t stream) {
    const float* xc = (const float*)d_in[0];
    const float* yc = (const float*)d_in[1];
    const float* xt = (const float*)d_in[2];
    const float* W0 = (const float*)d_in[3];
    const float* b0 = (const float*)d_in[4];
    const float* W1 = (const float*)d_in[5];
    const float* b1 = (const float*)d_in[6];
    const float* W2 = (const float*)d_in[7];
    const float* b2 = (const float*)d_in[8];
    const float* W3 = (const float*)d_in[9];
    const float* b3 = (const float*)d_in[10];
    float* out = (float*)d_out;

    k_fused<<<dim3(BB * NTT / NTB), dim3(512), 0, stream>>>(xc, yc, xt, W0, b0,
                                                            W1, b1, W2, b2, W3,
                                                            b3, out);
}